// Round 10
// baseline (574.071 us; speedup 1.0000x reference)
//
#include <hip/hip_runtime.h>
#include <stdint.h>

// ---------------- problem constants ----------------
#define HW_      102400          // 320*320
#define C_       256
#define N_       1024
#define P_       2               // pairs
#define TILES_   1600            // 64-px tiles per src plane
#define CHUNKS_  32              // chunks per (pair, n-block)
#define TPC_     50              // tiles per chunk (3200 px = 10 image rows)
#define STAGES_  200             // TPC_ * 4 k-quarter stages
#define NB_      4               // n-blocks of 256 keypoints
#define K2_      144.269504088896340f   // 100 / ln(2)
#define MOFF_    (-72.134752044448170f) // -K2_ * 0.5 (fixed softmax max; cosine logits <= ~1.02)

typedef __attribute__((ext_vector_type(8)))  short bf16x8;
typedef __attribute__((ext_vector_type(16))) float f32x16;

// ws layout (bytes):
//   tgt bf16 : [0, 1MB)       2*1024*256 bf16, [p][n][c]
//   partials : [1MB, 3MB)     2*32*2*1024 float4 (S,U,V,-)
//   PN       : [4MB, +100MB)  normalized src bf16 in per-(tile, h, kq) 4KB STRIPS:
//              strip dword = kkI*256 + hi*128 + r'*4 + dd   (kkI<4, hi<2, r'<32)
//              channel of dword dd (at kk = kq*4+kkI) = kk*16 + hi*8 + 2*dd(+1)
//              strip base dword = (((p*1600+tile)*2 + h)*4 + kq) * 1024
#define WS_TGT_OFF  0
#define WS_PAR_OFF  (1u << 20)
#define WS_PN_OFF   (4u << 20)

__device__ __forceinline__ uint32_t packbf(float a, float b) {
  uint32_t r;
  asm("v_cvt_pk_bf16_f32 %0, %1, %2" : "=v"(r) : "v"(a), "v"(b));
  return r;
}
__device__ __forceinline__ float fexp2(float x) {
  return __builtin_amdgcn_exp2f(x);
}
__device__ __forceinline__ void dma16(const uint32_t* g, uint32_t* l) {
  // async global->LDS, 16B/lane; LDS dest = wave-uniform base + lane*16
  __builtin_amdgcn_global_load_lds(
      (const __attribute__((address_space(1))) uint32_t*)g,
      (__attribute__((address_space(3))) uint32_t*)l, 16, 0, 0);
}

// ---------------- kernel 1: (a) prenorm dense -> PN strips; (b) tgt normalize ----------------
__global__ __launch_bounds__(256)
void k_pre(const float* __restrict__ dense, const float* __restrict__ kdesc,
           const float* __restrict__ kscores, uint32_t* __restrict__ PN,
           uint16_t* __restrict__ tgt, float* __restrict__ out) {
  __shared__ float part[16][64];
  __shared__ float sinv[64];
  const int bid = blockIdx.x;
  if (bid < P_ * TILES_) {
    const int p = bid / TILES_, tile = bid % TILES_;
    const int t   = threadIdx.x;
    const int px4 = (t & 15) * 4;          // 4 consecutive px rows (stay in one 32-half)
    const int cg  = t >> 4;                // global k-slice kk = cg (16 ch each)
    const float* src = dense + (size_t)(p * 2) * C_ * HW_ + (size_t)(cg * 16) * HW_
                     + tile * 64 + px4;    // src ids 0,2
    float v[16][4];
    #pragma unroll
    for (int cc = 0; cc < 16; ++cc) {
      const float4 qd = *(const float4*)(src + (size_t)cc * HW_);
      v[cc][0] = qd.x; v[cc][1] = qd.y; v[cc][2] = qd.z; v[cc][3] = qd.w;
    }
    float ps[4] = {0.f, 0.f, 0.f, 0.f};
    #pragma unroll
    for (int cc = 0; cc < 16; ++cc) {
      #pragma unroll
      for (int i = 0; i < 4; ++i) ps[i] = fmaf(v[cc][i], v[cc][i], ps[i]);
    }
    #pragma unroll
    for (int i = 0; i < 4; ++i) part[cg][px4 + i] = ps[i];
    __syncthreads();
    if (t < 64) {
      float s = 0.f;
      #pragma unroll
      for (int g = 0; g < 16; ++g) s += part[g][t];
      sinv[t] = 1.f / fmaxf(sqrtf(s), 1e-12f);
    }
    __syncthreads();
    const int kq  = cg >> 2;               // k-quarter
    const int kkI = cg & 3;                // kk within quarter
    #pragma unroll
    for (int i = 0; i < 4; ++i) {
      const int r  = px4 + i;
      const int hh = r >> 5, rp = r & 31;
      const float iv = sinv[r];
      uint32_t* d = PN + ((((size_t)(p * TILES_ + tile) * 2 + hh) * 4 + kq) << 10)
                  + kkI * 256 + rp * 4;
      uint4 A, B;
      A.x = packbf(v[0][i] * iv,  v[1][i] * iv);    // ch cg*16+0..7  (hi=0)
      A.y = packbf(v[2][i] * iv,  v[3][i] * iv);
      A.z = packbf(v[4][i] * iv,  v[5][i] * iv);
      A.w = packbf(v[6][i] * iv,  v[7][i] * iv);
      B.x = packbf(v[8][i] * iv,  v[9][i] * iv);    // ch cg*16+8..15 (hi=1)
      B.y = packbf(v[10][i] * iv, v[11][i] * iv);
      B.z = packbf(v[12][i] * iv, v[13][i] * iv);
      B.w = packbf(v[14][i] * iv, v[15][i] * iv);
      *(uint4*)&d[0]   = A;
      *(uint4*)&d[128] = B;
    }
  } else {
    // ---- tgt keypoint descriptors -> normalized bf16 [p][n][c]; copy weights ----
    const int t = (bid - P_ * TILES_) * 256 + threadIdx.x;   // 0..2047
    const int p = t >> 10, n = t & 1023;
    const float* src = kdesc + (size_t)(p * 2 + 1) * C_ * N_ + n;   // tgt ids 1,3
    float s = 0.f;
    #pragma unroll 16
    for (int c = 0; c < C_; ++c) { const float v2 = src[c * N_]; s = fmaf(v2, v2, s); }
    const float inv = 1.f / fmaxf(sqrtf(s), 1e-12f);
    uint32_t* dst = (uint32_t*)(tgt + (size_t)t * C_);
    #pragma unroll 4
    for (int c8 = 0; c8 < C_; c8 += 8) {
      uint4 wv;
      wv.x = packbf(src[(c8 + 0) * N_] * inv, src[(c8 + 1) * N_] * inv);
      wv.y = packbf(src[(c8 + 2) * N_] * inv, src[(c8 + 3) * N_] * inv);
      wv.z = packbf(src[(c8 + 4) * N_] * inv, src[(c8 + 5) * N_] * inv);
      wv.w = packbf(src[(c8 + 6) * N_] * inv, src[(c8 + 7) * N_] * inv);
      *(uint4*)&dst[c8 / 2] = wv;
    }
    out[4096 + t] = kscores[(p * 2 + 1) * N_ + n];   // match_weights
  }
}

// ---------------- kernel 2: SELF-PACED waves, zero barriers ----------------
// block: 512 thr (8 waves = 2(h) x 4(q)); 64 n/wave; grid 256 = 1 block/CU (128KB LDS).
// Each wave owns 4 private 4KB LDS slots and pipelines its own strips with per-wave
// counted vmcnt (depth 2): issue stage g+2 -> vmcnt(8) -> stage g resident. No syncthreads.
// Stage = 4 dma16 + 4 ds_read_b128 + 8 MFMA(32x32); softmax every 4th stage.
__global__ __launch_bounds__(512, 2)
void k_main(const uint32_t* __restrict__ PN, const uint16_t* __restrict__ tgt,
            float4* __restrict__ partials) {
  __shared__ uint32_t lds[32768];   // 8 waves x 4 slots x 1024 dwords = 128 KB

  // ---- XCD co-locating decode: same (p,chunk) -> bids {x, x+8, x+16, x+24} ----
  const int bid = blockIdx.x;              // 0..255
  const int xcd = bid & 7;
  const int rr  = bid >> 3;                // 0..31
  const int nb  = rr & 3;
  const int grp = xcd + 8 * (rr >> 2);     // 0..63 = (p, chunk)
  const int p     = grp >> 5;
  const int chunk = grp & 31;

  const int t    = threadIdx.x;
  const int lane = t & 63;
  const int w    = t >> 6;                 // 0..7
  const int l31  = lane & 31;
  const int hi   = lane >> 5;
  const int h    = w & 1;                  // px half (32 rows of each tile)
  const int q    = w >> 1;                 // n slice (64 n)

  // ---- B fragments: Bf[j][kk] lane holds B[k=kk*16+hi*8+e][n=nbase+j*32+l31] ----
  bf16x8 Bf[2][16];                        // 128 VGPR
  const int nbase = nb * 256 + q * 64;
  #pragma unroll
  for (int j = 0; j < 2; ++j) {
    const uint16_t* tp = tgt + (size_t)(p * N_ + nbase + j * 32 + l31) * C_ + hi * 8;
    #pragma unroll
    for (int kk = 0; kk < 16; ++kk) Bf[j][kk] = *(const bf16x8*)(tp + kk * 16);
  }

  float stS[2], stU[2], stV[2];
  #pragma unroll
  for (int j = 0; j < 2; ++j) { stS[j] = 0.f; stU[j] = 0.f; stV[j] = 0.f; }

  const int roff = hi * 128 + l31 * 4;     // per-lane dword offset inside a slot kk-block
  uint32_t* wslot = &lds[w * 4096];        // this wave's 4 slots
  // strip base (dwords>>10) for stage g: pb + (g>>2)*8 + (g&3)   (h strips interleave)
  const size_t pb = ((size_t)(p * TILES_ + chunk * TPC_) * 2 + h) * 4;
  const uint32_t* PNl = PN + lane * 4;

  // ---- prologue: issue stages 0,1 ----
  {
    const uint32_t* s0 = PNl + ((pb + 0) << 10);
    uint32_t* d0 = wslot;
    dma16(s0, d0); dma16(s0 + 256, d0 + 256); dma16(s0 + 512, d0 + 512); dma16(s0 + 768, d0 + 768);
    const uint32_t* s1 = PNl + ((pb + 1) << 10);
    uint32_t* d1 = wslot + 1024;
    dma16(s1, d1); dma16(s1 + 256, d1 + 256); dma16(s1 + 512, d1 + 512); dma16(s1 + 768, d1 + 768);
  }

  f32x16 acc0, acc1;
  #pragma unroll
  for (int r = 0; r < 16; ++r) { acc0[r] = 0.f; acc1[r] = 0.f; }

  float u0f = 0.f, v0f = (float)(chunk * 10);
  for (int g = 0; g < STAGES_; ++g) {
    // ---- depth-2 prefetch + per-wave counted wait ----
    if (g + 2 < STAGES_) {
      const uint32_t* s = PNl + ((pb + (size_t)(((g + 2) >> 2) * 8 + ((g + 2) & 3))) << 10);
      uint32_t* d = wslot + ((g + 2) & 3) * 1024;
      dma16(s, d); dma16(s + 256, d + 256); dma16(s + 512, d + 512); dma16(s + 768, d + 768);
      asm volatile("s_waitcnt vmcnt(8)" ::: "memory");   // stage g resident
    } else if (g + 1 < STAGES_) {
      asm volatile("s_waitcnt vmcnt(4)" ::: "memory");
    } else {
      asm volatile("s_waitcnt vmcnt(0)" ::: "memory");
    }
    __builtin_amdgcn_sched_barrier(0);

    const uint32_t* slot = wslot + (g & 3) * 1024;
    const int kb = (g & 3) * 4;
    __builtin_amdgcn_s_setprio(1);
    #pragma unroll
    for (int kkI = 0; kkI < 4; ++kkI) {
      const bf16x8 a = *(const bf16x8*)&slot[kkI * 256 + roff];
      acc0 = __builtin_amdgcn_mfma_f32_32x32x16_bf16(a, Bf[0][kb + kkI], acc0, 0, 0, 0);
      acc1 = __builtin_amdgcn_mfma_f32_32x32x16_bf16(a, Bf[1][kb + kkI], acc1, 0, 0, 0);
    }
    __builtin_amdgcn_s_setprio(0);

    // ---- tile complete: fixed-max softmax + soft-argmax; reset acc ----
    if ((g & 3) == 3) {
      const float ub = u0f + (float)(h * 32 + 4 * hi);   // u of this lane's r=0 element
      float tS0 = 0.f, tC0 = 0.f, tS1 = 0.f, tC1 = 0.f;
      #pragma unroll
      for (int r = 0; r < 16; ++r) {
        const float cr = (float)((r & 3) + 8 * (r >> 2));
        const float e0 = fexp2(fmaf(K2_, acc0[r], MOFF_));
        const float e1 = fexp2(fmaf(K2_, acc1[r], MOFF_));
        tS0 += e0; tC0 = fmaf(e0, cr, tC0);
        tS1 += e1; tC1 = fmaf(e1, cr, tC1);
        acc0[r] = 0.f; acc1[r] = 0.f;
      }
      stS[0] += tS0; stU[0] = fmaf(ub, tS0, stU[0] + tC0); stV[0] = fmaf(v0f, tS0, stV[0]);
      stS[1] += tS1; stU[1] = fmaf(ub, tS1, stU[1] + tC1); stV[1] = fmaf(v0f, tS1, stV[1]);
      u0f += 64.f;
      if (u0f > 290.f) { u0f = 0.f; v0f += 1.f; }   // u0 cycles 0,64,128,192,256
    }
  }

  // ---- merge hi halves (disjoint px rows, same n) ----
  #pragma unroll
  for (int j = 0; j < 2; ++j) {
    float S = stS[j], U = stU[j], V = stV[j];
    S += __shfl_xor(S, 32, 64); U += __shfl_xor(U, 32, 64); V += __shfl_xor(V, 32, 64);
    if (lane < 32) {
      const int n = nbase + j * 32 + l31;
      partials[((size_t)(p * CHUNKS_ + chunk) * 2 + h) * N_ + n] = make_float4(S, U, V, 0.f);
    }
  }
}

// ---------------- kernel 3: sum 64 partials per (p, n) -> coords; ids ----------------
__global__ void k_final(const float4* __restrict__ partials, float* __restrict__ out) {
  const int t = blockIdx.x * blockDim.x + threadIdx.x;   // 0..2047
  const int p = t >> 10, n = t & 1023;
  float S = 0.f, U = 0.f, V = 0.f;
  #pragma unroll 4
  for (int s = 0; s < 2 * CHUNKS_; ++s) {
    const float4 v = partials[((size_t)p * 2 * CHUNKS_ + s) * N_ + n];
    S += v.x; U += v.y; V += v.z;
  }
  out[(size_t)(p * N_ + n) * 2 + 0] = U / S;
  out[(size_t)(p * N_ + n) * 2 + 1] = V / S;
  if (t < 4) {
    const float ids[4] = {1.f, 3.f, 0.f, 2.f};  // tgt_ids then src_ids
    out[6144 + t] = ids[t];
  }
}

// ---------------- host launch ----------------
extern "C" void kernel_launch(void* const* d_in, const int* in_sizes, int n_in,
                              void* d_out, int out_size, void* d_ws, size_t ws_size,
                              hipStream_t stream) {
  const float* kscores = (const float*)d_in[0];   // (4,1,1024)
  const float* kdesc   = (const float*)d_in[1];   // (4,256,1024)
  const float* dense   = (const float*)d_in[2];   // (4,256,320,320)
  float* out = (float*)d_out;

  char* ws = (char*)d_ws;
  uint16_t* tgt = (uint16_t*)(ws + WS_TGT_OFF);
  float4*   par = (float4*)(ws + WS_PAR_OFF);
  uint32_t* PN  = (uint32_t*)(ws + WS_PN_OFF);

  k_pre<<<P_ * TILES_ + (P_ * N_) / 256, 256, 0, stream>>>(dense, kdesc, kscores, PN, tgt, out);
  k_main<<<P_ * NB_ * CHUNKS_, 512, 0, stream>>>(PN, tgt, par);
  k_final<<<(P_ * N_) / 256, 256, 0, stream>>>(par, out);
}